// Round 7
// baseline (354.647 us; speedup 1.0000x reference)
//
#include <hip/hip_runtime.h>
#include <hip/hip_bf16.h>

#define B_   16
#define NC_  1024
#define NQ_  128
#define D_   512

typedef __attribute__((ext_vector_type(8))) short bf16x8;
typedef __attribute__((ext_vector_type(4))) float f32x4;

// fp32 -> bf16 RTNE; scalar cast so compiler fuses pairs into v_cvt_pk_bf16_f32
__device__ __forceinline__ short f2bf(float x) {
    return __builtin_bit_cast(short, __float2bfloat16(x));
}

// Streaming pass: cb = bf16(c). Fully coalesced: 64B/lane read, 32B/lane write.
__global__ __launch_bounds__(256) void prep_c_kernel(
    const float* __restrict__ c, short* __restrict__ cb)
{
    const size_t t = (size_t)blockIdx.x * 256 + threadIdx.x;
    const float* src = c + t * 16;
    f32x4 v0 = *(const f32x4*)(src);
    f32x4 v1 = *(const f32x4*)(src + 4);
    f32x4 v2 = *(const f32x4*)(src + 8);
    f32x4 v3 = *(const f32x4*)(src + 12);
    bf16x8 o0, o1;
    o0[0] = f2bf(v0[0]); o0[1] = f2bf(v0[1]); o0[2] = f2bf(v0[2]); o0[3] = f2bf(v0[3]);
    o0[4] = f2bf(v1[0]); o0[5] = f2bf(v1[1]); o0[6] = f2bf(v1[2]); o0[7] = f2bf(v1[3]);
    o1[0] = f2bf(v2[0]); o1[1] = f2bf(v2[1]); o1[2] = f2bf(v2[2]); o1[3] = f2bf(v2[3]);
    o1[4] = f2bf(v3[0]); o1[5] = f2bf(v3[1]); o1[6] = f2bf(v3[2]); o1[7] = f2bf(v3[3]);
    *(bf16x8*)(cb + t * 16)     = o0;
    *(bf16x8*)(cb + t * 16 + 8) = o1;
}

// Pre-kernel: qw[b][j][d] = bf16(q*w_cq + w_c); qterm[b][j] = q . w_q
__global__ __launch_bounds__(256) void prep_kernel(
    const float* __restrict__ q, const float* __restrict__ kern,
    short* __restrict__ qw, float* __restrict__ qterm)
{
    const int tid  = threadIdx.x;
    const int lane = tid & 63;
    const int row  = blockIdx.x * 4 + (tid >> 6);   // 0..2047 (b*128 + j)
    const int k0   = lane * 8;
    const float* qr = q + (size_t)row * D_;
    f32x4 a0 = *(const f32x4*)(qr + k0);
    f32x4 a1 = *(const f32x4*)(qr + k0 + 4);
    f32x4 g0 = *(const f32x4*)(kern + 2 * D_ + k0);      // w_cq
    f32x4 g1 = *(const f32x4*)(kern + 2 * D_ + k0 + 4);
    f32x4 w0 = *(const f32x4*)(kern + D_ + k0);          // w_q
    f32x4 w1 = *(const f32x4*)(kern + D_ + k0 + 4);
    f32x4 h0 = *(const f32x4*)(kern + k0);               // w_c
    f32x4 h1 = *(const f32x4*)(kern + k0 + 4);
    bf16x8 o;
    o[0] = f2bf(a0[0] * g0[0] + h0[0]); o[1] = f2bf(a0[1] * g0[1] + h0[1]);
    o[2] = f2bf(a0[2] * g0[2] + h0[2]); o[3] = f2bf(a0[3] * g0[3] + h0[3]);
    o[4] = f2bf(a1[0] * g1[0] + h1[0]); o[5] = f2bf(a1[1] * g1[1] + h1[1]);
    o[6] = f2bf(a1[2] * g1[2] + h1[2]); o[7] = f2bf(a1[3] * g1[3] + h1[3]);
    *(bf16x8*)(qw + (size_t)row * D_ + k0) = o;
    float s = a0[0]*w0[0] + a0[1]*w0[1] + a0[2]*w0[2] + a0[3]*w0[3]
            + a1[0]*w1[0] + a1[1]*w1[1] + a1[2]*w1[2] + a1[3]*w1[3];
    s += __shfl_xor(s, 1);  s += __shfl_xor(s, 2);  s += __shfl_xor(s, 4);
    s += __shfl_xor(s, 8);  s += __shfl_xor(s, 16); s += __shfl_xor(s, 32);
    if (lane == 0) qterm[row] = s;
}

// INSTRUMENTED sim: K-loop repeated 16x (accumulate 16x dot, scale by 1/16 —
// exact in fp32). Memory clobber per rep stops LICM from hoisting reloads.
// Purpose: force sim into rocprof top-5 with real counters; per-rep hot time
// = (dur_R7 - dur_R6)/15.
__global__ __launch_bounds__(256, 4) void sim_kernel(
    const short* __restrict__ cb, const short* __restrict__ qw,
    const float* __restrict__ qterm,
    const float* __restrict__ bias_p, float* __restrict__ out)
{
    const int bid  = blockIdx.x;
    const int b    = bid >> 6;          // 64 M-tiles per batch
    const int mt   = bid & 63;
    const int tid  = threadIdx.x;
    const int lane = tid & 63;
    const int wn   = tid >> 6;          // wave col 0..3
    const int rif  = lane & 15;
    const int kg   = lane >> 4;

    const int rowbase = mt * 16;
    const short* cA = cb + ((size_t)(b * NC_ + rowbase + rif)) * D_ + kg * 8;
    const short* qB = qw + ((size_t)(b * NQ_ + wn * 32 + rif)) * D_ + kg * 8;

    f32x4 acc0 = {}, acc1 = {};

    #pragma unroll 1
    for (int rep = 0; rep < 16; ++rep) {
        asm volatile("" ::: "memory");  // force reload each rep (defeat LICM)
        bf16x8 av[4], b0[4], b1[4];
        #pragma unroll
        for (int s = 0; s < 3; ++s) {
            const int k = s * 32;
            av[s] = *(const bf16x8*)(cA + k);
            b0[s] = *(const bf16x8*)(qB + k);
            b1[s] = *(const bf16x8*)(qB + k + 16 * D_);
        }
        #pragma unroll
        for (int it = 0; it < 16; ++it) {
            const int cur = it & 3;
            if (it + 3 < 16) {
                const int nxt = (it + 3) & 3;
                const int k = (it + 3) * 32;
                av[nxt] = *(const bf16x8*)(cA + k);
                b0[nxt] = *(const bf16x8*)(qB + k);
                b1[nxt] = *(const bf16x8*)(qB + k + 16 * D_);
            }
            acc0 = __builtin_amdgcn_mfma_f32_16x16x32_bf16(av[cur], b0[cur], acc0, 0, 0, 0);
            acc1 = __builtin_amdgcn_mfma_f32_16x16x32_bf16(av[cur], b1[cur], acc1, 0, 0, 0);
        }
    }
    // undo the 16x accumulation (exact: 16 = 2^4)
    #pragma unroll
    for (int r = 0; r < 4; ++r) { acc0[r] *= 0.0625f; acc1[r] *= 0.0625f; }

    const float bias = *bias_p;
    const float* qt = qterm + b * NQ_ + wn * 32 + rif;
    const float base0 = qt[0]  + bias;
    const float base1 = qt[16] + bias;
    float* o = out + ((size_t)(b * NC_ + rowbase + kg * 4)) * NQ_ + wn * 32 + rif;
    #pragma unroll
    for (int r = 0; r < 4; ++r) {
        o[(size_t)r * NQ_ +  0] = acc0[r] + base0;
        o[(size_t)r * NQ_ + 16] = acc1[r] + base1;
    }
}

extern "C" void kernel_launch(void* const* d_in, const int* in_sizes, int n_in,
                              void* d_out, int out_size, void* d_ws, size_t ws_size,
                              hipStream_t stream) {
    const float* c    = (const float*)d_in[0];
    const float* q    = (const float*)d_in[1];
    const float* kern = (const float*)d_in[2];
    const float* bias = (const float*)d_in[3];
    float* out = (float*)d_out;

    // ws layout: qw bf16 [2048][512] | qterm f32 [2048] | cb bf16 [16][1024][512]
    short* qw    = (short*)d_ws;
    float* qterm = (float*)((char*)d_ws + (size_t)2048 * 512 * 2);
    short* cb    = (short*)((char*)d_ws + (size_t)2048 * 512 * 2 + 2048 * 4);

    prep_c_kernel<<<2048, 256, 0, stream>>>(c, cb);
    prep_kernel<<<512, 256, 0, stream>>>(q, kern, qw, qterm);
    sim_kernel<<<1024, 256, 0, stream>>>(cb, qw, qterm, bias, out);
}

// Round 8
// 20.326 us; speedup vs baseline: 17.4480x; 17.4480x over previous
//
#include <hip/hip_runtime.h>
#include <hip/hip_bf16.h>

#define B_   16
#define NC_  1024
#define NQ_  128
#define D_   512
#define BM   32
#define BK   64
#define NKT  8        // K-tiles: 512/64

typedef __attribute__((ext_vector_type(8))) short bf16x8;
typedef __attribute__((ext_vector_type(4))) float f32x4;
typedef __attribute__((address_space(3))) char lds_char;
typedef const __attribute__((address_space(1))) char g_char;

// fp32 -> bf16 RTNE
__device__ __forceinline__ short f2bf(float x) {
    return __builtin_bit_cast(short, __float2bfloat16(x));
}

// Pre-kernel: qw[b][j][d] = bf16(q*w_cq + w_c); qterm[b][j] = q . w_q
__global__ __launch_bounds__(256) void prep_kernel(
    const float* __restrict__ q, const float* __restrict__ kern,
    short* __restrict__ qw, float* __restrict__ qterm)
{
    const int tid  = threadIdx.x;
    const int lane = tid & 63;
    const int row  = blockIdx.x * 4 + (tid >> 6);   // 0..2047 (b*128 + j)
    const int k0   = lane * 8;
    const float* qr = q + (size_t)row * D_;
    f32x4 a0 = *(const f32x4*)(qr + k0);
    f32x4 a1 = *(const f32x4*)(qr + k0 + 4);
    f32x4 g0 = *(const f32x4*)(kern + 2 * D_ + k0);      // w_cq
    f32x4 g1 = *(const f32x4*)(kern + 2 * D_ + k0 + 4);
    f32x4 w0 = *(const f32x4*)(kern + D_ + k0);          // w_q
    f32x4 w1 = *(const f32x4*)(kern + D_ + k0 + 4);
    f32x4 h0 = *(const f32x4*)(kern + k0);               // w_c
    f32x4 h1 = *(const f32x4*)(kern + k0 + 4);
    bf16x8 o;
    o[0] = f2bf(a0[0] * g0[0] + h0[0]); o[1] = f2bf(a0[1] * g0[1] + h0[1]);
    o[2] = f2bf(a0[2] * g0[2] + h0[2]); o[3] = f2bf(a0[3] * g0[3] + h0[3]);
    o[4] = f2bf(a1[0] * g1[0] + h1[0]); o[5] = f2bf(a1[1] * g1[1] + h1[1]);
    o[6] = f2bf(a1[2] * g1[2] + h1[2]); o[7] = f2bf(a1[3] * g1[3] + h1[3]);
    *(bf16x8*)(qw + (size_t)row * D_ + k0) = o;
    float s = a0[0]*w0[0] + a0[1]*w0[1] + a0[2]*w0[2] + a0[3]*w0[3]
            + a1[0]*w1[0] + a1[1]*w1[1] + a1[2]*w1[2] + a1[3]*w1[3];
    s += __shfl_xor(s, 1);  s += __shfl_xor(s, 2);  s += __shfl_xor(s, 4);
    s += __shfl_xor(s, 8);  s += __shfl_xor(s, 16); s += __shfl_xor(s, 32);
    if (lane == 0) qterm[row] = s;
}

// Main GEMM: out[b][i][j] = (c[b][i] . qw[b][j]) + qterm[b][j] + bias
// T3 minimal 2-phase: stage(next) via global_load_lds -> compute(cur) -> vmcnt(0)+barrier.
// LDS per buf: A fp32 [32][64] swizzled (8KB) | B bf16 [128][64] swizzled (16KB).
// Swizzle (both tiles): byte_in_row ^= (row&7)<<4  (involution; staging pre-swizzles the
// GLOBAL source per rule #21, LDS dest stays linear for global_load_lds).
// 4 waves split N (32 cols each); per wave per K-tile: 8 A-reads(b128)+4 B-reads, 8 MFMA.
__global__ __launch_bounds__(256, 2) void sim_kernel(
    const float* __restrict__ c, const short* __restrict__ qw,
    const float* __restrict__ qterm, const float* __restrict__ bias_p,
    float* __restrict__ out)
{
    __shared__ char lds[2][24576];

    const int bid  = blockIdx.x;
    const int b    = bid >> 5;          // 32 M-tiles per batch
    const int mt   = bid & 31;
    const int tid  = threadIdx.x;
    const int lane = tid & 63;
    const int w    = tid >> 6;          // wave 0..3 -> N columns w*32..w*32+31
    const int rif  = lane & 15;
    const int kg   = lane >> 4;

    // --- staging source addresses (per lane), for k-tile 0 ---
    // A: 2 wave-loads of 1KB; chunk=w*2+l covers rows chunk*4..+3 (row = 256B)
    const char* asrc0; const char* asrc1; int adst0, adst1;
    {
        int ch0 = w * 2, ch1 = w * 2 + 1;
        int r0 = ch0 * 4 + (lane >> 4), r1 = ch1 * 4 + (lane >> 4);
        int s0 = ((lane & 15) * 16) ^ ((r0 & 7) << 4);
        int s1 = ((lane & 15) * 16) ^ ((r1 & 7) << 4);
        asrc0 = (const char*)c + ((size_t)(b * NC_ + mt * BM + r0) * D_) * 4 + s0;
        asrc1 = (const char*)c + ((size_t)(b * NC_ + mt * BM + r1) * D_) * 4 + s1;
        adst0 = ch0 * 1024 + lane * 16;
        adst1 = ch1 * 1024 + lane * 16;
    }
    // B: 4 wave-loads of 1KB; chunk=w*4+l covers j-rows chunk*8..+7 (row = 128B)
    const char* bsrc[4]; int bdst[4];
    #pragma unroll
    for (int l = 0; l < 4; ++l) {
        int ch = w * 4 + l;
        int j  = ch * 8 + (lane >> 3);
        int so = ((lane & 7) * 16) ^ ((j & 7) << 4);
        bsrc[l] = (const char*)qw + ((size_t)(b * NQ_ + j) * D_) * 2 + so;
        bdst[l] = 8192 + ch * 1024 + lane * 16;
    }

#define STAGE(BUF, KT)                                                            \
    do {                                                                          \
        lds_char* L_ = (lds_char*)&lds[(BUF)][0];                                 \
        __builtin_amdgcn_global_load_lds((g_char*)(asrc0 + (KT) * 256),           \
                                         (lds_char*)(L_ + adst0), 16, 0, 0);      \
        __builtin_amdgcn_global_load_lds((g_char*)(asrc1 + (KT) * 256),           \
                                         (lds_char*)(L_ + adst1), 16, 0, 0);      \
        __builtin_amdgcn_global_load_lds((g_char*)(bsrc[0] + (KT) * 128),         \
                                         (lds_char*)(L_ + bdst[0]), 16, 0, 0);    \
        __builtin_amdgcn_global_load_lds((g_char*)(bsrc[1] + (KT) * 128),         \
                                         (lds_char*)(L_ + bdst[1]), 16, 0, 0);    \
        __builtin_amdgcn_global_load_lds((g_char*)(bsrc[2] + (KT) * 128),         \
                                         (lds_char*)(L_ + bdst[2]), 16, 0, 0);    \
        __builtin_amdgcn_global_load_lds((g_char*)(bsrc[3] + (KT) * 128),         \
                                         (lds_char*)(L_ + bdst[3]), 16, 0, 0);    \
    } while (0)

    f32x4 acc[2][2] = {};

    STAGE(0, 0);
    asm volatile("s_waitcnt vmcnt(0)" ::: "memory");
    __syncthreads();

    int buf = 0;
    #pragma unroll 1
    for (int kt = 0; kt < NKT; ++kt) {
        if (kt + 1 < NKT) STAGE(buf ^ 1, kt + 1);

        const char* L = &lds[buf][0];
        #pragma unroll
        for (int kk = 0; kk < 2; ++kk) {
            bf16x8 af[2];
            #pragma unroll
            for (int mf = 0; mf < 2; ++mf) {
                int row = mf * 16 + rif;
                int sw  = (row & 7) << 4;
                f32x4 v0 = *(const f32x4*)(L + row * 256 + ((kk * 128 + kg * 32 +  0) ^ sw));
                f32x4 v1 = *(const f32x4*)(L + row * 256 + ((kk * 128 + kg * 32 + 16) ^ sw));
                bf16x8 a;
                a[0] = f2bf(v0[0]); a[1] = f2bf(v0[1]); a[2] = f2bf(v0[2]); a[3] = f2bf(v0[3]);
                a[4] = f2bf(v1[0]); a[5] = f2bf(v1[1]); a[6] = f2bf(v1[2]); a[7] = f2bf(v1[3]);
                af[mf] = a;
            }
            #pragma unroll
            for (int nf = 0; nf < 2; ++nf) {
                int j  = w * 32 + nf * 16 + rif;
                bf16x8 bfr = *(const bf16x8*)(L + 8192 + j * 128 + ((kk * 64 + kg * 16) ^ ((j & 7) << 4)));
                acc[0][nf] = __builtin_amdgcn_mfma_f32_16x16x32_bf16(af[0], bfr, acc[0][nf], 0, 0, 0);
                acc[1][nf] = __builtin_amdgcn_mfma_f32_16x16x32_bf16(af[1], bfr, acc[1][nf], 0, 0, 0);
            }
        }

        asm volatile("s_waitcnt vmcnt(0)" ::: "memory");
        __syncthreads();
        buf ^= 1;
    }
#undef STAGE

    const float bias = *bias_p;
    #pragma unroll
    for (int nf = 0; nf < 2; ++nf) {
        const float qt = qterm[b * NQ_ + w * 32 + nf * 16 + rif] + bias;
        #pragma unroll
        for (int mf = 0; mf < 2; ++mf) {
            float* o = out + ((size_t)(b * NC_ + mt * BM + mf * 16 + kg * 4)) * NQ_
                     + w * 32 + nf * 16 + rif;
            #pragma unroll
            for (int r = 0; r < 4; ++r)
                o[(size_t)r * NQ_] = acc[mf][nf][r] + qt;
        }
    }
}

extern "C" void kernel_launch(void* const* d_in, const int* in_sizes, int n_in,
                              void* d_out, int out_size, void* d_ws, size_t ws_size,
                              hipStream_t stream) {
    const float* c    = (const float*)d_in[0];
    const float* q    = (const float*)d_in[1];
    const float* kern = (const float*)d_in[2];
    const float* bias = (const float*)d_in[3];
    float* out = (float*)d_out;

    // ws layout: qw bf16 [2048][512] (2 MiB) | qterm f32 [2048]
    short* qw    = (short*)d_ws;
    float* qterm = (float*)((char*)d_ws + (size_t)2048 * 512 * 2);

    prep_kernel<<<512, 256, 0, stream>>>(q, kern, qw, qterm);
    sim_kernel<<<512, 256, 0, stream>>>(c, qw, qterm, bias, out);  // 16 batches x 32 M-tiles
}